// Round 18
// baseline (199.108 us; speedup 1.0000x reference)
//
#include <hip/hip_runtime.h>
#include <hip/hip_bf16.h>

#define SEQ  4096
#define EMB  768
#define NH   12
#define HD   64
#define HID  3072
#define QKVC 2304

typedef __attribute__((ext_vector_type(8))) short bf16x8;
typedef __attribute__((ext_vector_type(4))) float f32x4;

#define MFMA16(a,b,c) __builtin_amdgcn_mfma_f32_16x16x32_bf16(a,b,c,0,0,0)

// log2(e)/8 : Q pre-scale so attn softmax works directly in log2 domain
#define QSCL 0.18033688f
// fixed softmax shift (log2 domain): scores*QSCL have sigma~1.4, max~8.5 over
// 2e8 samples; 16 gives >5-sigma headroom and bf16/fp32 range safety by ~80 sigma.
#define MFIX 16.0f

__device__ __forceinline__ unsigned short f2bf(float f){
  union { float f; unsigned u; } c; c.f = f;
  unsigned r = c.u + 0x7FFFu + ((c.u >> 16) & 1u);
  return (unsigned short)(r >> 16);
}

__device__ __forceinline__ float bf2f(unsigned short u){
  union { unsigned u; float f; } c; c.u = (unsigned)u << 16; return c.f;
}

__device__ __forceinline__ unsigned cvtpk(float a, float b){
  unsigned r;
  asm("v_cvt_pk_bf16_f32 %0, %1, %2" : "=v"(r) : "v"(a), "v"(b));
  return r;
}

// tanh-form GELU via exp2: gelu(x) = x*u/(1+u), u = exp2(x*(A + B*x^2))
__device__ __forceinline__ float gelu_f(float x){
  float x2 = x * x;
  float u  = __builtin_amdgcn_exp2f(x * fmaf(x2, 0.1029433f, 2.3022082f));
  return x * u * __builtin_amdgcn_rcpf(1.f + u);
}

__device__ __forceinline__ void gload_lds16(const unsigned short* g, unsigned short* l){
  __builtin_amdgcn_global_load_lds(
      (const __attribute__((address_space(1))) unsigned int*)g,
      (__attribute__((address_space(3))) unsigned int*)l, 16, 0, 0);
}

// ---------------- merged: LayerNorm1 (blocks 0..SEQ-1) + weight cvt (rest) ----------------
__global__ __launch_bounds__(256) void pre_kernel(
    const float* __restrict__ x, const float* __restrict__ w, const float* __restrict__ b,
    unsigned short* __restrict__ out,
    const float* __restrict__ s0, unsigned short* __restrict__ d0, int n0,
    const float* __restrict__ s1, unsigned short* __restrict__ d1, int n1,
    const float* __restrict__ s2, unsigned short* __restrict__ d2, int n2,
    const float* __restrict__ s3, unsigned short* __restrict__ d3, int n3)
{
  const int t = threadIdx.x;
  if (blockIdx.x < SEQ){
    const int row = blockIdx.x;
    const float* xr = x + (size_t)row * EMB;
    float v0 = xr[t], v1 = xr[t + 256], v2 = xr[t + 512];
    float s  = v0 + v1 + v2;
    float s2 = v0*v0 + v1*v1 + v2*v2;
    #pragma unroll
    for (int off = 32; off; off >>= 1){ s += __shfl_down(s, off); s2 += __shfl_down(s2, off); }
    __shared__ float rs[4], rq[4], st[2];
    int wv = t >> 6;
    if ((t & 63) == 0){ rs[wv] = s; rq[wv] = s2; }
    __syncthreads();
    if (t == 0){
      float S  = rs[0] + rs[1] + rs[2] + rs[3];
      float S2 = rq[0] + rq[1] + rq[2] + rq[3];
      float mu  = S * (1.f / 768.f);
      float var = S2 * (1.f / 768.f) - mu * mu;
      st[0] = mu; st[1] = rsqrtf(var + 1e-5f);
    }
    __syncthreads();
    float mu = st[0], rstd = st[1];
    unsigned short* orow = out + (size_t)row * EMB;
    orow[t]       = f2bf((v0 - mu) * rstd * w[t]       + b[t]);
    orow[t + 256] = f2bf((v1 - mu) * rstd * w[t + 256] + b[t + 256]);
    orow[t + 512] = f2bf((v2 - mu) * rstd * w[t + 512] + b[t + 512]);
  } else {
    long e = ((long)(blockIdx.x - SEQ) * 256 + t) << 2;
    const float* s; unsigned short* d;
    if (e < n0){ s = s0; d = d0; }
    else if ((e -= n0) < n1){ s = s1; d = d1; }
    else if ((e -= n1) < n2){ s = s2; d = d2; }
    else if ((e -= n2) < n3){ s = s3; d = d3; }
    else return;
    float4 v = *(const float4*)(s + e);
    ushort4 u;
    u.x = f2bf(v.x); u.y = f2bf(v.y); u.z = f2bf(v.z); u.w = f2bf(v.w);
    *(ushort4*)(d + e) = u;
  }
}

// ---------------- LayerNorm (one row per block) ----------------
__global__ __launch_bounds__(256) void ln_kernel(const float* __restrict__ x,
    const float* __restrict__ w, const float* __restrict__ b,
    unsigned short* __restrict__ out)
{
  const int row = blockIdx.x;
  const float* xr = x + (size_t)row * EMB;
  const int t = threadIdx.x;
  float v0 = xr[t], v1 = xr[t + 256], v2 = xr[t + 512];
  float s  = v0 + v1 + v2;
  float s2 = v0*v0 + v1*v1 + v2*v2;
  #pragma unroll
  for (int off = 32; off; off >>= 1){ s += __shfl_down(s, off); s2 += __shfl_down(s2, off); }
  __shared__ float rs[4], rq[4], st[2];
  int wv = t >> 6;
  if ((t & 63) == 0){ rs[wv] = s; rq[wv] = s2; }
  __syncthreads();
  if (t == 0){
    float S  = rs[0] + rs[1] + rs[2] + rs[3];
    float S2 = rq[0] + rq[1] + rq[2] + rq[3];
    float mu  = S * (1.f / 768.f);
    float var = S2 * (1.f / 768.f) - mu * mu;
    st[0] = mu; st[1] = rsqrtf(var + 1e-5f);
  }
  __syncthreads();
  float mu = st[0], rstd = st[1];
  unsigned short* orow = out + (size_t)row * EMB;
  orow[t]       = f2bf((v0 - mu) * rstd * w[t]       + b[t]);
  orow[t + 256] = f2bf((v1 - mu) * rstd * w[t + 256] + b[t + 256]);
  orow[t + 512] = f2bf((v2 - mu) * rstd * w[t + 512] + b[t + 512]);
}

// ---------------- GEMM: C[M,N] = A[M,K] * B[N,K]^T (+bias, epilogue) ----------------
// 1-D grid with bijective XCD swizzle (T1). ALL tiles: 3-buffer depth-2
// prefetch with counted vmcnt(4) + raw s_barrier (T4), 3 blocks/CU.
// EPI: 0 bias->bf16; 1 bias+GELU->bf16; 2 bias+residual->f32; 3 bias, scale cols<EMB ->bf16
template<int EPI, int BM, int BN, int BK>
__global__ __launch_bounds__(256, 3) void gemm_kernel(
    const unsigned short* __restrict__ A, const unsigned short* __restrict__ B,
    const float* __restrict__ bias, const float* __restrict__ res,
    unsigned short* __restrict__ Ob, float* __restrict__ Of,
    int M, int N, int K)
{
  constexpr int MF  = BM / 32;
  constexpr int NF  = BN / 32;
  constexpr int KS  = BK / 32;
  constexpr int CPR = BK / 8;
  constexpr int AIT = BM * BK / 2048;
  constexpr int BIT = BN * BK / 2048;
  __shared__ unsigned short sA[3][BM * BK];
  __shared__ unsigned short sB[3][BN * BK];
  const int tid  = threadIdx.x;
  const int w    = tid >> 6, lane = tid & 63;
  const int wr   = w >> 1,   wc   = w & 1;
  const int l15  = lane & 15, l4  = lane >> 4;
  const int nb  = gridDim.x;
  const int lin = blockIdx.x;
  const int v   = (lin & 7) * (nb >> 3) + (lin >> 3);
  const int gN  = N / BN;
  const int tm  = v / gN, tn = v % gN;
  const unsigned short* Ab = A + (size_t)tm * BM * K;
  const unsigned short* Bb = B + (size_t)tn * BN * K;

  f32x4 acc[MF][NF];
  #pragma unroll
  for (int m = 0; m < MF; ++m)
    #pragma unroll
    for (int n = 0; n < NF; ++n){ acc[m][n][0]=0.f; acc[m][n][1]=0.f; acc[m][n][2]=0.f; acc[m][n][3]=0.f; }

  #define GSTAGE(buf, kt) { \
    const int k0_ = (kt) * BK; \
    _Pragma("unroll") \
    for (int i = 0; i < AIT; ++i){ \
      int c = i * 256 + tid; int row = c / CPR; int skc = (c % CPR) ^ (row & (CPR - 1)); \
      gload_lds16(Ab + (size_t)row * K + k0_ + skc * 8, &sA[buf][(i * 256 + w * 64) * 8]); } \
    _Pragma("unroll") \
    for (int i = 0; i < BIT; ++i){ \
      int c = i * 256 + tid; int row = c / CPR; int skc = (c % CPR) ^ (row & (CPR - 1)); \
      gload_lds16(Bb + (size_t)row * K + k0_ + skc * 8, &sB[buf][(i * 256 + w * 64) * 8]); }}

  #define GCOMPUTE(buf) { \
    _Pragma("unroll") \
    for (int ks = 0; ks < KS; ++ks){ \
      bf16x8 af[MF], bg[NF]; \
      _Pragma("unroll") \
      for (int m = 0; m < MF; ++m){ \
        int row = wr * (BM / 2) + m * 16 + l15; \
        int kc  = ks * 4 + l4; \
        af[m] = *(const bf16x8*)&sA[buf][row * BK + ((kc ^ (row & (CPR - 1))) << 3)]; } \
      _Pragma("unroll") \
      for (int n = 0; n < NF; ++n){ \
        int row = wc * (BN / 2) + n * 16 + l15; \
        int kc  = ks * 4 + l4; \
        bg[n] = *(const bf16x8*)&sB[buf][row * BK + ((kc ^ (row & (CPR - 1))) << 3)]; } \
      _Pragma("unroll") \
      for (int m = 0; m < MF; ++m) \
        _Pragma("unroll") \
        for (int n = 0; n < NF; ++n) \
          acc[m][n] = MFMA16(af[m], bg[n], acc[m][n]); }}

  const int nk = K / BK;
  GSTAGE(0, 0);
  GSTAGE(1, 1);
  for (int kt = 0; kt < nk; ++kt){
    if (kt + 2 < nk) asm volatile("s_waitcnt vmcnt(4)" ::: "memory");
    else             asm volatile("s_waitcnt vmcnt(0)" ::: "memory");
    __builtin_amdgcn_s_barrier();
    if (kt + 2 < nk) GSTAGE((kt + 2) % 3, kt + 2);
    GCOMPUTE(kt % 3);
  }
  #undef GSTAGE
  #undef GCOMPUTE

  #pragma unroll
  for (int m = 0; m < MF; ++m){
    int row0 = tm * BM + wr * (BM / 2) + m * 16 + l4 * 4;
    #pragma unroll
    for (int n = 0; n < NF; ++n){
      int col = tn * BN + wc * (BN / 2) + n * 16 + l15;
      float bv = bias[col];
      #pragma unroll
      for (int r = 0; r < 4; ++r){
        int row = row0 + r;
        float v2 = acc[m][n][r] + bv;
        if (EPI == 0){
          Ob[(size_t)row * N + col] = f2bf(v2);
        } else if (EPI == 1){
          Ob[(size_t)row * N + col] = f2bf(gelu_f(v2));
        } else if (EPI == 3){
          if (col < EMB) v2 *= QSCL;
          Ob[(size_t)row * N + col] = f2bf(v2);
        } else {
          v2 += res[(size_t)row * N + col];
          Of[(size_t)row * N + col] = v2;
        }
      }
    }
  }
}

// ---------------- out-proj GEMM with fused split-KV combine ----------------
// C = combine(pO,pl) @ Wout^T + bias + residual -> f32 out.
// BM=BN=BK=64, 2-buffer sync pipeline. K-step kt == head (768/64 == NH), so
// the A-tile for step kt is (pO0[head]+pO1[head]) * 1/l[head][q] -- combined
// in registers (T14 issue-early / commit-late) and ds_written to the same
// XOR-swizzled slots the reader expects. Deletes comb kernel + attnb traffic.
__global__ __launch_bounds__(256, 3) void gemm_op_kernel(
    const unsigned short* __restrict__ pO, const float* __restrict__ pl,
    const unsigned short* __restrict__ B, const float* __restrict__ bias,
    const float* __restrict__ res, float* __restrict__ Of)
{
  __shared__ unsigned short sA[2][64 * 64];
  __shared__ unsigned short sB[2][64 * 64];
  const int tid  = threadIdx.x;
  const int w    = tid >> 6, lane = tid & 63;
  const int wr   = w >> 1,   wc   = w & 1;
  const int l15  = lane & 15, l4  = lane >> 4;
  const int nb  = gridDim.x;
  const int lin = blockIdx.x;
  const int v   = (lin & 7) * (nb >> 3) + (lin >> 3);
  const int gN  = EMB / 64;                  // 12
  const int tm  = v / gN, tn = v % gN;
  const unsigned short* Bb = B + (size_t)tn * 64 * EMB;

  f32x4 acc[2][2];
  #pragma unroll
  for (int m = 0; m < 2; ++m)
    #pragma unroll
    for (int n = 0; n < 2; ++n){ acc[m][n][0]=0.f; acc[m][n][1]=0.f; acc[m][n][2]=0.f; acc[m][n][3]=0.f; }

  // A staging constants: chunk i=0 -> row tid>>3, i=1 -> row 32+(tid>>3)
  const int arow = tid >> 3;
  const int askc = (tid & 7) ^ (arow & 7);
  const int q0 = tm * 64 + arow, q1 = q0 + 32;
  const size_t SK1 = (size_t)NH * SEQ * 64;   // pO slice stride

  bf16x8 a00, a01, a10, a11;
  float lt0, lt1;

  #define ALOAD(t) { \
    const unsigned short* pa = pO + ((size_t)(t) * SEQ + q0) * 64 + askc * 8; \
    const unsigned short* pb_ = pO + ((size_t)(t) * SEQ + q1) * 64 + askc * 8; \
    a00 = *(const bf16x8*)pa;  a01 = *(const bf16x8*)(pa + SK1); \
    a10 = *(const bf16x8*)pb_; a11 = *(const bf16x8*)(pb_ + SK1); \
    lt0 = pl[(size_t)(t) * SEQ + q0] + pl[(size_t)(NH + (t)) * SEQ + q0]; \
    lt1 = pl[(size_t)(t) * SEQ + q1] + pl[(size_t)(NH + (t)) * SEQ + q1]; }

  #define ACOMMIT(buf) { \
    float i0 = 1.f / lt0, i1 = 1.f / lt1; \
    union { unsigned uw[4]; bf16x8 v; } u0, u1; \
    _Pragma("unroll") \
    for (int j = 0; j < 4; ++j){ \
      u0.uw[j] = cvtpk((bf2f((unsigned short)a00[2*j])   + bf2f((unsigned short)a01[2*j]))   * i0, \
                       (bf2f((unsigned short)a00[2*j+1]) + bf2f((unsigned short)a01[2*j+1])) * i0); \
      u1.uw[j] = cvtpk((bf2f((unsigned short)a10[2*j])   + bf2f((unsigned short)a11[2*j]))   * i1, \
                       (bf2f((unsigned short)a10[2*j+1]) + bf2f((unsigned short)a11[2*j+1])) * i1); \
    } \
    *(bf16x8*)&sA[buf][tid * 8]         = u0.v; \
    *(bf16x8*)&sA[buf][(256 + tid) * 8] = u1.v; }

  #define BSTAGE(buf, kt) { \
    const int k0_ = (kt) * 64; \
    _Pragma("unroll") \
    for (int i = 0; i < 2; ++i){ \
      int c = i * 256 + tid; int row = c >> 3; int skc = (c & 7) ^ (row & 7); \
      gload_lds16(Bb + (size_t)row * EMB + k0_ + skc * 8, &sB[buf][(i * 256 + w * 64) * 8]); }}

  #define OCOMPUTE(buf) { \
    _Pragma("unroll") \
    for (int ks = 0; ks < 2; ++ks){ \
      bf16x8 af[2], bg[2]; \
      _Pragma("unroll") \
      for (int m = 0; m < 2; ++m){ \
        int row = wr * 32 + m * 16 + l15; \
        int kc  = ks * 4 + l4; \
        af[m] = *(const bf16x8*)&sA[buf][row * 64 + ((kc ^ (row & 7)) << 3)]; } \
      _Pragma("unroll") \
      for (int n = 0; n < 2; ++n){ \
        int row = wc * 32 + n * 16 + l15; \
        int kc  = ks * 4 + l4; \
        bg[n] = *(const bf16x8*)&sB[buf][row * 64 + ((kc ^ (row & 7)) << 3)]; } \
      _Pragma("unroll") \
      for (int m = 0; m < 2; ++m) \
        _Pragma("unroll") \
        for (int n = 0; n < 2; ++n) \
          acc[m][n] = MFMA16(af[m], bg[n], acc[m][n]); }}

  // prologue
  ALOAD(0);
  BSTAGE(0, 0);
  ACOMMIT(0);
  __syncthreads();

  int cur = 0;
  for (int kt = 0; kt < NH; ++kt){
    const bool pre = (kt + 1 < NH);
    if (pre){
      ALOAD(kt + 1);             // global loads land under compute
      BSTAGE(cur ^ 1, kt + 1);
    }
    OCOMPUTE(cur);
    if (pre) ACOMMIT(cur ^ 1);
    __syncthreads();             // drains vmcnt (B) + lgkm (A writes)
    cur ^= 1;
  }
  #undef ALOAD
  #undef ACOMMIT
  #undef BSTAGE
  #undef OCOMPUTE

  #pragma unroll
  for (int m = 0; m < 2; ++m){
    int row0 = tm * 64 + wr * 32 + m * 16 + l4 * 4;
    #pragma unroll
    for (int n = 0; n < 2; ++n){
      int col = tn * 64 + wc * 32 + n * 16 + l15;
      float bv = bias[col];
      #pragma unroll
      for (int r = 0; r < 4; ++r){
        int row = row0 + r;
        float v2 = acc[m][n][r] + bv + res[(size_t)row * EMB + col];
        Of[(size_t)row * EMB + col] = v2;
      }
    }
  }
}

// ---------------- flash attention v8 (R15-proven): split-KV/2, fixed-m ----------------
// 768 blocks. Q pre-scaled by QSCL; softmax uses FIXED shift MFIX (shift-
// invariance; range-safe by >5 sigma) -> no max reduce, no defer/rescale.
__global__ __launch_bounds__(256, 3) void attn_kernel(
    const unsigned short* __restrict__ qkv,
    unsigned short* __restrict__ pO, float* __restrict__ pl)
{
  __shared__ unsigned short sK[2][64 * 64];
  __shared__ unsigned short sVt[2][64 * 64];
  __shared__ unsigned short sEp[4][16 * 72];
  const int tid = threadIdx.x, w = tid >> 6, lane = tid & 63;
  const int l15 = lane & 15, l4 = lane >> 4;

  const int bid  = blockIdx.x;
  const int v_id = (bid & 7) * 96 + (bid >> 3);   // 0..767, XCD-contiguous
  const int head = v_id >> 6;
  const int r6   = v_id & 63;
  const int qt   = r6 >> 1;        // 0..31
  const int sk   = r6 & 1;         // KV half

  const int koff = EMB + head * HD;
  const int voff = 2 * EMB + head * HD;
  const int qbase = qt * 128 + w * 32;
  const int tbase = sk * 32;

  bf16x8 qf[2][2];
  #pragma unroll
  for (int qg = 0; qg < 2; ++qg){
    const unsigned short* qp = qkv + (size_t)(qbase + qg * 16 + l15) * QKVC + head * HD + l4 * 8;
    qf[qg][0] = *(const bf16x8*)qp;
    qf[qg][1] = *(const bf16x8*)(qp + 32);
  }

  f32x4 oaccT[4][2];
  #pragma unroll
  for (int i = 0; i < 4; ++i)
    #pragma unroll
    for (int qg = 0; qg < 2; ++qg){ oaccT[i][qg][0]=0.f; oaccT[i][qg][1]=0.f; oaccT[i][qg][2]=0.f; oaccT[i][qg][3]=0.f; }
  float l0 = 0.f, l1 = 0.f;

  const int krow = tid >> 3;
  const int kskc = (tid & 7) ^ (krow & 7);
  const int vp_  = tid >> 3;
  const int d0   = (tid & 7) * 8;
  const int w16  = vp_ & 15;
  const int qpos = (w16 & 1) | (((w16 >> 3) & 1) << 1) | (((w16 >> 1) & 3) << 2);
  const int Pc   = ((vp_ >> 4) << 2) | (qpos >> 2);
  const int Ps   = qpos & 3;

  #define KSTAGE(buf, t) { \
    const int kv0_ = (t) << 6; \
    gload_lds16(qkv + (size_t)(kv0_ + krow) * QKVC + koff + kskc * 8,      &sK[buf][(w * 64) * 8]); \
    gload_lds16(qkv + (size_t)(kv0_ + 32 + krow) * QKVC + koff + kskc * 8, &sK[buf][(256 + w * 64) * 8]); }

  #define VLOAD(t) { \
    const unsigned short* vp = qkv + (size_t)(((t) << 6) + vp_ * 2) * QKVC + voff + d0; \
    va = *(const bf16x8*)vp; \
    vb = *(const bf16x8*)(vp + QKVC); }

  #define VCOMMIT(buf) { \
    _Pragma("unroll") \
    for (int i = 0; i < 8; ++i){ \
      unsigned pk = (unsigned)(unsigned short)va[i] | ((unsigned)(unsigned short)vb[i] << 16); \
      *(unsigned*)&sVt[buf][(d0 + i) * 64 + ((Pc ^ (tid & 7) ^ i) << 3) + Ps * 2] = pk; \
    } }

  bf16x8 va, vb;
  KSTAGE(0, tbase);
  VLOAD(tbase);
  VCOMMIT(0);

  for (int tt = 0; tt < 32; ++tt){
    const int cur = tt & 1;
    __syncthreads();
    const bool pre = (tt < 31);
    if (pre){
      KSTAGE(cur ^ 1, tbase + tt + 1);
      VLOAD(tbase + tt + 1);
    }

    // ---- QK^T (swapped): sf[nb][qg] = S^T[kv=16nb+4l4+r][q], log2 domain ----
    f32x4 sf[4][2];
    #pragma unroll
    for (int i = 0; i < 4; ++i)
      #pragma unroll
      for (int qg = 0; qg < 2; ++qg){ sf[i][qg][0]=0.f; sf[i][qg][1]=0.f; sf[i][qg][2]=0.f; sf[i][qg][3]=0.f; }
    __builtin_amdgcn_s_setprio(1);
    #pragma unroll
    for (int ks = 0; ks < 2; ++ks){
      bf16x8 kf[4];
      #pragma unroll
      for (int nb = 0; nb < 4; ++nb){
        int row = 16 * nb + l15;
        kf[nb] = *(const bf16x8*)&sK[cur][(row * 8 + ((4 * ks + l4) ^ (row & 7))) * 8];
      }
      #pragma unroll
      for (int nb = 0; nb < 4; ++nb){
        sf[nb][0] = MFMA16(kf[nb], qf[0][ks], sf[nb][0]);
        sf[nb][1] = MFMA16(kf[nb], qf[1][ks], sf[nb][1]);
      }
    }
    __builtin_amdgcn_s_setprio(0);

    // ---- fixed-m softmax: P = exp2(sf - MFIX); l-sum off critical path ----
    unsigned pbw[2][2][4];   // [qg][ks][word]; slot j holds kv=32ks+16(j>>2)+4l4+(j&3)
    {
      float ps0 = 0.f, ps1 = 0.f;
      #pragma unroll
      for (int nb = 0; nb < 4; ++nb){
        float p0[4], p1[4];
        #pragma unroll
        for (int r = 0; r < 4; ++r){
          p0[r] = __builtin_amdgcn_exp2f(sf[nb][0][r] - MFIX); ps0 += p0[r];
          p1[r] = __builtin_amdgcn_exp2f(sf[nb][1][r] - MFIX); ps1 += p1[r];
        }
        pbw[0][nb >> 1][(nb & 1) * 2]     = cvtpk(p0[0], p0[1]);
        pbw[0][nb >> 1][(nb & 1) * 2 + 1] = cvtpk(p0[2], p0[3]);
        pbw[1][nb >> 1][(nb & 1) * 2]     = cvtpk(p1[0], p1[1]);
        pbw[1][nb >> 1][(nb & 1) * 2 + 1] = cvtpk(p1[2], p1[3]);
      }
      ps0 += __shfl_xor(ps0, 16); ps0 += __shfl_xor(ps0, 32);
      ps1 += __shfl_xor(ps1, 16); ps1 += __shfl_xor(ps1, 32);
      l0 += ps0; l1 += ps1;
    }

    // ---- O^T += V^T * P^T ----
    __builtin_amdgcn_s_setprio(1);
    {
      bf16x8 vv[2][4];
      #pragma unroll
      for (int ks = 0; ks < 2; ++ks)
        #pragma unroll
        for (int db = 0; db < 4; ++db){
          int d = 16 * db + l15;
          int cp = (4 * ks + l4) ^ ((d >> 3) & 7) ^ (d & 7);
          vv[ks][db] = *(const bf16x8*)&sVt[cur][d * 64 + cp * 8];
        }
      union { unsigned uw[4]; bf16x8 v; } pb;
      #pragma unroll
      for (int qg = 0; qg < 2; ++qg){
        bf16x8 pb0, pb1;
        pb.uw[0]=pbw[qg][0][0]; pb.uw[1]=pbw[qg][0][1]; pb.uw[2]=pbw[qg][0][2]; pb.uw[3]=pbw[qg][0][3]; pb0 = pb.v;
        pb.uw[0]=pbw[qg][1][0]; pb.uw[1]=pbw[qg][1][1]; pb.uw[2]=pbw[qg][1][2]; pb.uw[3]=pbw[qg][1][3]; pb1 = pb.v;
        #pragma unroll
        for (int db = 0; db < 4; ++db){
          oaccT[db][qg] = MFMA16(vv[0][db], pb0, oaccT[db][qg]);
          oaccT[db][qg] = MFMA16(vv[1][db], pb1, oaccT[db][qg]);
        }
      }
    }
    __builtin_amdgcn_s_setprio(0);

    if (pre) VCOMMIT(cur ^ 1);
  }

  // ---- epilogue: unnormalized O^T -> pO rows, l -> pl ----
  #pragma unroll
  for (int qg = 0; qg < 2; ++qg){
    unsigned short* sPw = sEp[w];
    #pragma unroll
    for (int db = 0; db < 4; ++db)
      #pragma unroll
      for (int dw = 0; dw < 2; ++dw){
        unsigned pk = cvtpk(oaccT[db][qg][2 * dw], oaccT[db][qg][2 * dw + 1]);
        *(unsigned*)&sPw[l15 * 72 + 16 * db + 4 * l4 + 2 * dw] = pk;
      }
    int qe = lane >> 2, de = (lane & 3) * 16;
    bf16x8 r0 = *(const bf16x8*)&sPw[qe * 72 + de];
    bf16x8 r1 = *(const bf16x8*)&sPw[qe * 72 + de + 8];
    unsigned short* op = pO + ((size_t)(sk * NH + head) * SEQ + qbase + qg * 16 + qe) * 64 + de;
    *(bf16x8*)op = r0;
    *(bf16x8*)(op + 8) = r1;
  }
  if (lane < 16){
    size_t r = (size_t)(sk * NH + head) * SEQ + qbase + l15;
    pl[r]      = l0;
    pl[r + 16] = l1;
  }
  #undef KSTAGE
  #undef VLOAD
  #undef VCOMMIT
}

// ---------------- host launch ----------------
extern "C" void kernel_launch(void* const* d_in, const int* in_sizes, int n_in,
                              void* d_out, int out_size, void* d_ws, size_t ws_size,
                              hipStream_t stream)
{
  const float* x    = (const float*)d_in[0];
  const float* ln1w = (const float*)d_in[1];
  const float* ln1b = (const float*)d_in[2];
  const float* qkvw = (const float*)d_in[3];
  const float* qkvb = (const float*)d_in[4];
  const float* outw = (const float*)d_in[5];
  const float* outb = (const float*)d_in[6];
  const float* ln2w = (const float*)d_in[7];
  const float* ln2b = (const float*)d_in[8];
  const float* fc1w = (const float*)d_in[9];
  const float* fc1b = (const float*)d_in[10];
  const float* fc2w = (const float*)d_in[11];
  const float* fc2b = (const float*)d_in[12];
  float* out = (float*)d_out;

  char* ws = (char*)d_ws;
  unsigned short* wqkv = (unsigned short*)ws; ws += (size_t)QKVC * EMB * 2;
  unsigned short* wout = (unsigned short*)ws; ws += (size_t)EMB * EMB * 2;
  unsigned short* wfc1 = (unsigned short*)ws; ws += (size_t)HID * EMB * 2;
  unsigned short* wfc2 = (unsigned short*)ws; ws += (size_t)EMB * HID * 2;
  unsigned short* h1   = (unsigned short*)ws; ws += (size_t)SEQ * EMB * 2;   // LN1 out
  unsigned short* qkv  = (unsigned short*)ws; ws += (size_t)SEQ * QKVC * 2;  // reused as h2
  unsigned short* h3   = (unsigned short*)ws; ws += (size_t)SEQ * HID * 2;   // MLP mid; attn partials overlay
  unsigned short* h2    = qkv;
  unsigned short* pO  = h3;
  float*          pl  = (float*)(h3 + (size_t)2 * NH * SEQ * 64);

  const int n0 = QKVC * EMB, n1 = EMB * EMB, n2 = HID * EMB, n3 = EMB * HID;
  pre_kernel<<<SEQ + (n0 + n1 + n2 + n3) / 4 / 256, 256, 0, stream>>>(
      x, ln1w, ln1b, h1,
      qkvw, wqkv, n0, outw, wout, n1, fc1w, wfc1, n2, fc2w, wfc2, n3);

  gemm_kernel<3, 128, 128, 32><<<(SEQ / 128) * (QKVC / 128), 256, 0, stream>>>(
      h1, wqkv, qkvb, nullptr, qkv, nullptr, SEQ, QKVC, EMB);

  attn_kernel<<<SEQ / 128 * NH * 2, 256, 0, stream>>>(qkv, pO, pl);

  gemm_op_kernel<<<(SEQ / 64) * (EMB / 64), 256, 0, stream>>>(
      pO, pl, wout, outb, x, out);

  ln_kernel<<<SEQ, 256, 0, stream>>>(out, ln2w, ln2b, h2);

  gemm_kernel<1, 128, 128, 32><<<(SEQ / 128) * (HID / 128), 256, 0, stream>>>(
      h2, wfc1, fc1b, nullptr, h3, nullptr, SEQ, HID, EMB);

  gemm_kernel<2, 64, 64, 64><<<(SEQ / 64) * (EMB / 64), 256, 0, stream>>>(
      h3, wfc2, fc2b, out, nullptr, out, SEQ, EMB, HID);
}

// Round 20
// 195.178 us; speedup vs baseline: 1.0201x; 1.0201x over previous
//
#include <hip/hip_runtime.h>
#include <hip/hip_bf16.h>

#define SEQ  4096
#define EMB  768
#define NH   12
#define HD   64
#define HID  3072
#define QKVC 2304

typedef __attribute__((ext_vector_type(8))) short bf16x8;
typedef __attribute__((ext_vector_type(4))) float f32x4;

#define MFMA16(a,b,c) __builtin_amdgcn_mfma_f32_16x16x32_bf16(a,b,c,0,0,0)

// log2(e)/8 : Q pre-scale so attn softmax works directly in log2 domain
#define QSCL 0.18033688f
// fixed softmax shift (log2 domain): scores*QSCL have sigma~1.4, max~8.5 over
// 2e8 samples; 16 gives >5-sigma headroom and bf16/fp32 range safety by ~80 sigma.
#define MFIX 16.0f

__device__ __forceinline__ unsigned short f2bf(float f){
  union { float f; unsigned u; } c; c.f = f;
  unsigned r = c.u + 0x7FFFu + ((c.u >> 16) & 1u);
  return (unsigned short)(r >> 16);
}

__device__ __forceinline__ float bf2f(unsigned short u){
  union { unsigned u; float f; } c; c.u = (unsigned)u << 16; return c.f;
}

__device__ __forceinline__ unsigned cvtpk(float a, float b){
  unsigned r;
  asm("v_cvt_pk_bf16_f32 %0, %1, %2" : "=v"(r) : "v"(a), "v"(b));
  return r;
}

// tanh-form GELU via exp2: gelu(x) = x*u/(1+u), u = exp2(x*(A + B*x^2))
__device__ __forceinline__ float gelu_f(float x){
  float x2 = x * x;
  float u  = __builtin_amdgcn_exp2f(x * fmaf(x2, 0.1029433f, 2.3022082f));
  return x * u * __builtin_amdgcn_rcpf(1.f + u);
}

__device__ __forceinline__ void gload_lds16(const unsigned short* g, unsigned short* l){
  __builtin_amdgcn_global_load_lds(
      (const __attribute__((address_space(1))) unsigned int*)g,
      (__attribute__((address_space(3))) unsigned int*)l, 16, 0, 0);
}

// ---------------- merged: LayerNorm1 (blocks 0..SEQ-1) + weight cvt (rest) ----------------
__global__ __launch_bounds__(256) void pre_kernel(
    const float* __restrict__ x, const float* __restrict__ w, const float* __restrict__ b,
    unsigned short* __restrict__ out,
    const float* __restrict__ s0, unsigned short* __restrict__ d0, int n0,
    const float* __restrict__ s1, unsigned short* __restrict__ d1, int n1,
    const float* __restrict__ s2, unsigned short* __restrict__ d2, int n2,
    const float* __restrict__ s3, unsigned short* __restrict__ d3, int n3)
{
  const int t = threadIdx.x;
  if (blockIdx.x < SEQ){
    const int row = blockIdx.x;
    const float* xr = x + (size_t)row * EMB;
    float v0 = xr[t], v1 = xr[t + 256], v2 = xr[t + 512];
    float s  = v0 + v1 + v2;
    float s2 = v0*v0 + v1*v1 + v2*v2;
    #pragma unroll
    for (int off = 32; off; off >>= 1){ s += __shfl_down(s, off); s2 += __shfl_down(s2, off); }
    __shared__ float rs[4], rq[4], st[2];
    int wv = t >> 6;
    if ((t & 63) == 0){ rs[wv] = s; rq[wv] = s2; }
    __syncthreads();
    if (t == 0){
      float S  = rs[0] + rs[1] + rs[2] + rs[3];
      float S2 = rq[0] + rq[1] + rq[2] + rq[3];
      float mu  = S * (1.f / 768.f);
      float var = S2 * (1.f / 768.f) - mu * mu;
      st[0] = mu; st[1] = rsqrtf(var + 1e-5f);
    }
    __syncthreads();
    float mu = st[0], rstd = st[1];
    unsigned short* orow = out + (size_t)row * EMB;
    orow[t]       = f2bf((v0 - mu) * rstd * w[t]       + b[t]);
    orow[t + 256] = f2bf((v1 - mu) * rstd * w[t + 256] + b[t + 256]);
    orow[t + 512] = f2bf((v2 - mu) * rstd * w[t + 512] + b[t + 512]);
  } else {
    long e = ((long)(blockIdx.x - SEQ) * 256 + t) << 2;
    const float* s; unsigned short* d;
    if (e < n0){ s = s0; d = d0; }
    else if ((e -= n0) < n1){ s = s1; d = d1; }
    else if ((e -= n1) < n2){ s = s2; d = d2; }
    else if ((e -= n2) < n3){ s = s3; d = d3; }
    else return;
    float4 v = *(const float4*)(s + e);
    ushort4 u;
    u.x = f2bf(v.x); u.y = f2bf(v.y); u.z = f2bf(v.z); u.w = f2bf(v.w);
    *(ushort4*)(d + e) = u;
  }
}

// ---------------- LayerNorm (one row per block) ----------------
__global__ __launch_bounds__(256) void ln_kernel(const float* __restrict__ x,
    const float* __restrict__ w, const float* __restrict__ b,
    unsigned short* __restrict__ out)
{
  const int row = blockIdx.x;
  const float* xr = x + (size_t)row * EMB;
  const int t = threadIdx.x;
  float v0 = xr[t], v1 = xr[t + 256], v2 = xr[t + 512];
  float s  = v0 + v1 + v2;
  float s2 = v0*v0 + v1*v1 + v2*v2;
  #pragma unroll
  for (int off = 32; off; off >>= 1){ s += __shfl_down(s, off); s2 += __shfl_down(s2, off); }
  __shared__ float rs[4], rq[4], st[2];
  int wv = t >> 6;
  if ((t & 63) == 0){ rs[wv] = s; rq[wv] = s2; }
  __syncthreads();
  if (t == 0){
    float S  = rs[0] + rs[1] + rs[2] + rs[3];
    float S2 = rq[0] + rq[1] + rq[2] + rq[3];
    float mu  = S * (1.f / 768.f);
    float var = S2 * (1.f / 768.f) - mu * mu;
    st[0] = mu; st[1] = rsqrtf(var + 1e-5f);
  }
  __syncthreads();
  float mu = st[0], rstd = st[1];
  unsigned short* orow = out + (size_t)row * EMB;
  orow[t]       = f2bf((v0 - mu) * rstd * w[t]       + b[t]);
  orow[t + 256] = f2bf((v1 - mu) * rstd * w[t + 256] + b[t + 256]);
  orow[t + 512] = f2bf((v2 - mu) * rstd * w[t + 512] + b[t + 512]);
}

// ---------------- GEMM: C[M,N] = A[M,K] * B[N,K]^T (+bias, epilogue) ----------------
// 1-D grid with bijective XCD swizzle (T1). ALL tiles: 3-buffer depth-2
// prefetch with counted vmcnt(4) + raw s_barrier (T4), 3 blocks/CU.
// EPI: 0 bias->bf16; 1 bias+GELU->bf16; 2 bias+residual->f32; 3 bias, scale cols<EMB ->bf16
template<int EPI, int BM, int BN, int BK>
__global__ __launch_bounds__(256, 3) void gemm_kernel(
    const unsigned short* __restrict__ A, const unsigned short* __restrict__ B,
    const float* __restrict__ bias, const float* __restrict__ res,
    unsigned short* __restrict__ Ob, float* __restrict__ Of,
    int M, int N, int K)
{
  constexpr int MF  = BM / 32;
  constexpr int NF  = BN / 32;
  constexpr int KS  = BK / 32;
  constexpr int CPR = BK / 8;
  constexpr int AIT = BM * BK / 2048;
  constexpr int BIT = BN * BK / 2048;
  __shared__ unsigned short sA[3][BM * BK];
  __shared__ unsigned short sB[3][BN * BK];
  const int tid  = threadIdx.x;
  const int w    = tid >> 6, lane = tid & 63;
  const int wr   = w >> 1,   wc   = w & 1;
  const int l15  = lane & 15, l4  = lane >> 4;
  const int nb  = gridDim.x;
  const int lin = blockIdx.x;
  const int v   = (lin & 7) * (nb >> 3) + (lin >> 3);
  const int gN  = N / BN;
  const int tm  = v / gN, tn = v % gN;
  const unsigned short* Ab = A + (size_t)tm * BM * K;
  const unsigned short* Bb = B + (size_t)tn * BN * K;

  f32x4 acc[MF][NF];
  #pragma unroll
  for (int m = 0; m < MF; ++m)
    #pragma unroll
    for (int n = 0; n < NF; ++n){ acc[m][n][0]=0.f; acc[m][n][1]=0.f; acc[m][n][2]=0.f; acc[m][n][3]=0.f; }

  #define GSTAGE(buf, kt) { \
    const int k0_ = (kt) * BK; \
    _Pragma("unroll") \
    for (int i = 0; i < AIT; ++i){ \
      int c = i * 256 + tid; int row = c / CPR; int skc = (c % CPR) ^ (row & (CPR - 1)); \
      gload_lds16(Ab + (size_t)row * K + k0_ + skc * 8, &sA[buf][(i * 256 + w * 64) * 8]); } \
    _Pragma("unroll") \
    for (int i = 0; i < BIT; ++i){ \
      int c = i * 256 + tid; int row = c / CPR; int skc = (c % CPR) ^ (row & (CPR - 1)); \
      gload_lds16(Bb + (size_t)row * K + k0_ + skc * 8, &sB[buf][(i * 256 + w * 64) * 8]); }}

  #define GCOMPUTE(buf) { \
    _Pragma("unroll") \
    for (int ks = 0; ks < KS; ++ks){ \
      bf16x8 af[MF], bg[NF]; \
      _Pragma("unroll") \
      for (int m = 0; m < MF; ++m){ \
        int row = wr * (BM / 2) + m * 16 + l15; \
        int kc  = ks * 4 + l4; \
        af[m] = *(const bf16x8*)&sA[buf][row * BK + ((kc ^ (row & (CPR - 1))) << 3)]; } \
      _Pragma("unroll") \
      for (int n = 0; n < NF; ++n){ \
        int row = wc * (BN / 2) + n * 16 + l15; \
        int kc  = ks * 4 + l4; \
        bg[n] = *(const bf16x8*)&sB[buf][row * BK + ((kc ^ (row & (CPR - 1))) << 3)]; } \
      _Pragma("unroll") \
      for (int m = 0; m < MF; ++m) \
        _Pragma("unroll") \
        for (int n = 0; n < NF; ++n) \
          acc[m][n] = MFMA16(af[m], bg[n], acc[m][n]); }}

  const int nk = K / BK;
  GSTAGE(0, 0);
  GSTAGE(1, 1);
  for (int kt = 0; kt < nk; ++kt){
    if (kt + 2 < nk) asm volatile("s_waitcnt vmcnt(4)" ::: "memory");
    else             asm volatile("s_waitcnt vmcnt(0)" ::: "memory");
    __builtin_amdgcn_s_barrier();
    if (kt + 2 < nk) GSTAGE((kt + 2) % 3, kt + 2);
    GCOMPUTE(kt % 3);
  }
  #undef GSTAGE
  #undef GCOMPUTE

  #pragma unroll
  for (int m = 0; m < MF; ++m){
    int row0 = tm * BM + wr * (BM / 2) + m * 16 + l4 * 4;
    #pragma unroll
    for (int n = 0; n < NF; ++n){
      int col = tn * BN + wc * (BN / 2) + n * 16 + l15;
      float bv = bias[col];
      #pragma unroll
      for (int r = 0; r < 4; ++r){
        int row = row0 + r;
        float v2 = acc[m][n][r] + bv;
        if (EPI == 0){
          Ob[(size_t)row * N + col] = f2bf(v2);
        } else if (EPI == 1){
          Ob[(size_t)row * N + col] = f2bf(gelu_f(v2));
        } else if (EPI == 3){
          if (col < EMB) v2 *= QSCL;
          Ob[(size_t)row * N + col] = f2bf(v2);
        } else {
          v2 += res[(size_t)row * N + col];
          Of[(size_t)row * N + col] = v2;
        }
      }
    }
  }
}

// ---------------- flash attention v8b: split-KV/2, fixed-m, deferred l-reduce ----------------
// 768 blocks. Q pre-scaled by QSCL; softmax uses FIXED shift MFIX. l is
// accumulated lane-locally per tile; the cross-lane shfl reduction runs ONCE
// in the epilogue (linearity: sums commute).
__global__ __launch_bounds__(256, 3) void attn_kernel(
    const unsigned short* __restrict__ qkv,
    unsigned short* __restrict__ pO, float* __restrict__ pl)
{
  __shared__ unsigned short sK[2][64 * 64];
  __shared__ unsigned short sVt[2][64 * 64];
  __shared__ unsigned short sEp[4][16 * 72];
  const int tid = threadIdx.x, w = tid >> 6, lane = tid & 63;
  const int l15 = lane & 15, l4 = lane >> 4;

  const int bid  = blockIdx.x;
  const int v_id = (bid & 7) * 96 + (bid >> 3);   // 0..767, XCD-contiguous
  const int head = v_id >> 6;
  const int r6   = v_id & 63;
  const int qt   = r6 >> 1;        // 0..31
  const int sk   = r6 & 1;         // KV half

  const int koff = EMB + head * HD;
  const int voff = 2 * EMB + head * HD;
  const int qbase = qt * 128 + w * 32;
  const int tbase = sk * 32;

  bf16x8 qf[2][2];
  #pragma unroll
  for (int qg = 0; qg < 2; ++qg){
    const unsigned short* qp = qkv + (size_t)(qbase + qg * 16 + l15) * QKVC + head * HD + l4 * 8;
    qf[qg][0] = *(const bf16x8*)qp;
    qf[qg][1] = *(const bf16x8*)(qp + 32);
  }

  f32x4 oaccT[4][2];
  #pragma unroll
  for (int i = 0; i < 4; ++i)
    #pragma unroll
    for (int qg = 0; qg < 2; ++qg){ oaccT[i][qg][0]=0.f; oaccT[i][qg][1]=0.f; oaccT[i][qg][2]=0.f; oaccT[i][qg][3]=0.f; }
  float l0 = 0.f, l1 = 0.f;   // lane-local partials; reduced once at epilogue

  const int krow = tid >> 3;
  const int kskc = (tid & 7) ^ (krow & 7);
  const int vp_  = tid >> 3;
  const int d0   = (tid & 7) * 8;
  const int w16  = vp_ & 15;
  const int qpos = (w16 & 1) | (((w16 >> 3) & 1) << 1) | (((w16 >> 1) & 3) << 2);
  const int Pc   = ((vp_ >> 4) << 2) | (qpos >> 2);
  const int Ps   = qpos & 3;

  #define KSTAGE(buf, t) { \
    const int kv0_ = (t) << 6; \
    gload_lds16(qkv + (size_t)(kv0_ + krow) * QKVC + koff + kskc * 8,      &sK[buf][(w * 64) * 8]); \
    gload_lds16(qkv + (size_t)(kv0_ + 32 + krow) * QKVC + koff + kskc * 8, &sK[buf][(256 + w * 64) * 8]); }

  #define VLOAD(t) { \
    const unsigned short* vp = qkv + (size_t)(((t) << 6) + vp_ * 2) * QKVC + voff + d0; \
    va = *(const bf16x8*)vp; \
    vb = *(const bf16x8*)(vp + QKVC); }

  #define VCOMMIT(buf) { \
    _Pragma("unroll") \
    for (int i = 0; i < 8; ++i){ \
      unsigned pk = (unsigned)(unsigned short)va[i] | ((unsigned)(unsigned short)vb[i] << 16); \
      *(unsigned*)&sVt[buf][(d0 + i) * 64 + ((Pc ^ (tid & 7) ^ i) << 3) + Ps * 2] = pk; \
    } }

  bf16x8 va, vb;
  KSTAGE(0, tbase);
  VLOAD(tbase);
  VCOMMIT(0);

  for (int tt = 0; tt < 32; ++tt){
    const int cur = tt & 1;
    __syncthreads();
    const bool pre = (tt < 31);
    if (pre){
      KSTAGE(cur ^ 1, tbase + tt + 1);
      VLOAD(tbase + tt + 1);
    }

    // ---- QK^T (swapped): sf[nb][qg] = S^T[kv=16nb+4l4+r][q], log2 domain ----
    f32x4 sf[4][2];
    #pragma unroll
    for (int i = 0; i < 4; ++i)
      #pragma unroll
      for (int qg = 0; qg < 2; ++qg){ sf[i][qg][0]=0.f; sf[i][qg][1]=0.f; sf[i][qg][2]=0.f; sf[i][qg][3]=0.f; }
    __builtin_amdgcn_s_setprio(1);
    #pragma unroll
    for (int ks = 0; ks < 2; ++ks){
      bf16x8 kf[4];
      #pragma unroll
      for (int nb = 0; nb < 4; ++nb){
        int row = 16 * nb + l15;
        kf[nb] = *(const bf16x8*)&sK[cur][(row * 8 + ((4 * ks + l4) ^ (row & 7))) * 8];
      }
      #pragma unroll
      for (int nb = 0; nb < 4; ++nb){
        sf[nb][0] = MFMA16(kf[nb], qf[0][ks], sf[nb][0]);
        sf[nb][1] = MFMA16(kf[nb], qf[1][ks], sf[nb][1]);
      }
    }
    __builtin_amdgcn_s_setprio(0);

    // ---- fixed-m softmax: P = exp2(sf - MFIX); lane-local l partials ----
    unsigned pbw[2][2][4];   // [qg][ks][word]; slot j holds kv=32ks+16(j>>2)+4l4+(j&3)
    {
      float ps0 = 0.f, ps1 = 0.f;
      #pragma unroll
      for (int nb = 0; nb < 4; ++nb){
        float p0[4], p1[4];
        #pragma unroll
        for (int r = 0; r < 4; ++r){
          p0[r] = __builtin_amdgcn_exp2f(sf[nb][0][r] - MFIX); ps0 += p0[r];
          p1[r] = __builtin_amdgcn_exp2f(sf[nb][1][r] - MFIX); ps1 += p1[r];
        }
        pbw[0][nb >> 1][(nb & 1) * 2]     = cvtpk(p0[0], p0[1]);
        pbw[0][nb >> 1][(nb & 1) * 2 + 1] = cvtpk(p0[2], p0[3]);
        pbw[1][nb >> 1][(nb & 1) * 2]     = cvtpk(p1[0], p1[1]);
        pbw[1][nb >> 1][(nb & 1) * 2 + 1] = cvtpk(p1[2], p1[3]);
      }
      l0 += ps0; l1 += ps1;    // no per-tile shuffles (deferred)
    }

    // ---- O^T += V^T * P^T ----
    __builtin_amdgcn_s_setprio(1);
    {
      bf16x8 vv[2][4];
      #pragma unroll
      for (int ks = 0; ks < 2; ++ks)
        #pragma unroll
        for (int db = 0; db < 4; ++db){
          int d = 16 * db + l15;
          int cp = (4 * ks + l4) ^ ((d >> 3) & 7) ^ (d & 7);
          vv[ks][db] = *(const bf16x8*)&sVt[cur][d * 64 + cp * 8];
        }
      union { unsigned uw[4]; bf16x8 v; } pb;
      #pragma unroll
      for (int qg = 0; qg < 2; ++qg){
        bf16x8 pb0, pb1;
        pb.uw[0]=pbw[qg][0][0]; pb.uw[1]=pbw[qg][0][1]; pb.uw[2]=pbw[qg][0][2]; pb.uw[3]=pbw[qg][0][3]; pb0 = pb.v;
        pb.uw[0]=pbw[qg][1][0]; pb.uw[1]=pbw[qg][1][1]; pb.uw[2]=pbw[qg][1][2]; pb.uw[3]=pbw[qg][1][3]; pb1 = pb.v;
        #pragma unroll
        for (int db = 0; db < 4; ++db){
          oaccT[db][qg] = MFMA16(vv[0][db], pb0, oaccT[db][qg]);
          oaccT[db][qg] = MFMA16(vv[1][db], pb1, oaccT[db][qg]);
        }
      }
    }
    __builtin_amdgcn_s_setprio(0);

    if (pre) VCOMMIT(cur ^ 1);
  }

  // ---- epilogue: one cross-lane l reduce; O^T -> pO rows, l -> pl ----
  l0 += __shfl_xor(l0, 16); l0 += __shfl_xor(l0, 32);
  l1 += __shfl_xor(l1, 16); l1 += __shfl_xor(l1, 32);
  #pragma unroll
  for (int qg = 0; qg < 2; ++qg){
    unsigned short* sPw = sEp[w];
    #pragma unroll
    for (int db = 0; db < 4; ++db)
      #pragma unroll
      for (int dw = 0; dw < 2; ++dw){
        unsigned pk = cvtpk(oaccT[db][qg][2 * dw], oaccT[db][qg][2 * dw + 1]);
        *(unsigned*)&sPw[l15 * 72 + 16 * db + 4 * l4 + 2 * dw] = pk;
      }
    int qe = lane >> 2, de = (lane & 3) * 16;
    bf16x8 r0 = *(const bf16x8*)&sPw[qe * 72 + de];
    bf16x8 r1 = *(const bf16x8*)&sPw[qe * 72 + de + 8];
    unsigned short* op = pO + ((size_t)(sk * NH + head) * SEQ + qbase + qg * 16 + qe) * 64 + de;
    *(bf16x8*)op = r0;
    *(bf16x8*)(op + 8) = r1;
  }
  if (lane < 16){
    size_t r = (size_t)(sk * NH + head) * SEQ + qbase + l15;
    pl[r]      = l0;
    pl[r + 16] = l1;
  }
  #undef KSTAGE
  #undef VLOAD
  #undef VCOMMIT
}

// ---------------- split-KV combine (fixed-m: plain sum + normalize) ----------------
__global__ __launch_bounds__(256) void comb_kernel(
    const unsigned short* __restrict__ pO, const float* __restrict__ pl,
    unsigned short* __restrict__ o)
{
  const int t = threadIdx.x;
  const int row = blockIdx.x * 64 + (t >> 2);
  const int dseg = (t & 3) * 16;
  float inv = 1.f / (pl[row] + pl[NH * SEQ + row]);
  const unsigned short* p0 = pO + (size_t)row * 64 + dseg;
  const unsigned short* p1 = p0 + (size_t)NH * SEQ * 64;
  bf16x8 x0 = *(const bf16x8*)p0, x1 = *(const bf16x8*)(p0 + 8);
  bf16x8 y0 = *(const bf16x8*)p1, y1 = *(const bf16x8*)(p1 + 8);
  const int head = row >> 12, q = row & (SEQ - 1);
  unsigned short* op = o + (size_t)q * EMB + head * HD + dseg;
  union { unsigned uw[4]; bf16x8 v; } r0, r1;
  #pragma unroll
  for (int i = 0; i < 4; ++i){
    r0.uw[i] = cvtpk(inv * (bf2f((unsigned short)x0[2*i])   + bf2f((unsigned short)y0[2*i])),
                     inv * (bf2f((unsigned short)x0[2*i+1]) + bf2f((unsigned short)y0[2*i+1])));
    r1.uw[i] = cvtpk(inv * (bf2f((unsigned short)x1[2*i])   + bf2f((unsigned short)y1[2*i])),
                     inv * (bf2f((unsigned short)x1[2*i+1]) + bf2f((unsigned short)y1[2*i+1])));
  }
  *(bf16x8*)op = r0.v;
  *(bf16x8*)(op + 8) = r1.v;
}

// ---------------- host launch ----------------
extern "C" void kernel_launch(void* const* d_in, const int* in_sizes, int n_in,
                              void* d_out, int out_size, void* d_ws, size_t ws_size,
                              hipStream_t stream)
{
  const float* x    = (const float*)d_in[0];
  const float* ln1w = (const float*)d_in[1];
  const float* ln1b = (const float*)d_in[2];
  const float* qkvw = (const float*)d_in[3];
  const float* qkvb = (const float*)d_in[4];
  const float* outw = (const float*)d_in[5];
  const float* outb = (const float*)d_in[6];
  const float* ln2w = (const float*)d_in[7];
  const float* ln2b = (const float*)d_in[8];
  const float* fc1w = (const float*)d_in[9];
  const float* fc1b = (const float*)d_in[10];
  const float* fc2w = (const float*)d_in[11];
  const float* fc2b = (const float*)d_in[12];
  float* out = (float*)d_out;

  char* ws = (char*)d_ws;
  unsigned short* wqkv = (unsigned short*)ws; ws += (size_t)QKVC * EMB * 2;
  unsigned short* wout = (unsigned short*)ws; ws += (size_t)EMB * EMB * 2;
  unsigned short* wfc1 = (unsigned short*)ws; ws += (size_t)HID * EMB * 2;
  unsigned short* wfc2 = (unsigned short*)ws; ws += (size_t)EMB * HID * 2;
  unsigned short* h1   = (unsigned short*)ws; ws += (size_t)SEQ * EMB * 2;   // attn out
  unsigned short* qkv  = (unsigned short*)ws; ws += (size_t)SEQ * QKVC * 2;  // reused as h2
  unsigned short* h3   = (unsigned short*)ws; ws += (size_t)SEQ * HID * 2;   // MLP mid; attn partials overlay
  unsigned short* attnb = h1;
  unsigned short* h2    = qkv;
  unsigned short* pO  = h3;
  float*          pl  = (float*)(h3 + (size_t)2 * NH * SEQ * 64);

  const int n0 = QKVC * EMB, n1 = EMB * EMB, n2 = HID * EMB, n3 = EMB * HID;
  pre_kernel<<<SEQ + (n0 + n1 + n2 + n3) / 4 / 256, 256, 0, stream>>>(
      x, ln1w, ln1b, h1,
      qkvw, wqkv, n0, outw, wout, n1, fc1w, wfc1, n2, fc2w, wfc2, n3);

  gemm_kernel<3, 128, 128, 32><<<(SEQ / 128) * (QKVC / 128), 256, 0, stream>>>(
      h1, wqkv, qkvb, nullptr, qkv, nullptr, SEQ, QKVC, EMB);

  attn_kernel<<<SEQ / 128 * NH * 2, 256, 0, stream>>>(qkv, pO, pl);
  comb_kernel<<<NH * SEQ / 64, 256, 0, stream>>>(pO, pl, attnb);

  gemm_kernel<2, 64, 64, 64><<<(SEQ / 64) * (EMB / 64), 256, 0, stream>>>(
      attnb, wout, outb, x, nullptr, out, SEQ, EMB, EMB);

  ln_kernel<<<SEQ, 256, 0, stream>>>(out, ln2w, ln2b, h2);

  gemm_kernel<1, 128, 128, 32><<<(SEQ / 128) * (HID / 128), 256, 0, stream>>>(
      h2, wfc1, fc1b, nullptr, h3, nullptr, SEQ, HID, EMB);

  gemm_kernel<2, 64, 64, 64><<<(SEQ / 64) * (EMB / 64), 256, 0, stream>>>(
      h3, wfc2, fc2b, out, nullptr, out, SEQ, EMB, HID);
}